// Round 10
// baseline (1314.577 us; speedup 1.0000x reference)
//
#include <hip/hip_runtime.h>

// HGCN on MI355X. logmap0(expmap0(v)) == v here, so the model reduces to:
//   t1 = sigmoid(segmean(feat@W1+b1)); t2 = sigmoid(segmean(t1@W2+b2))
//   out = relu(t2@W3+b3)@W4 + b4     (segmean commutes with the linear map;
//   deg-0 nodes: segmean = 0 -> value 0.5 exactly, handled via dz check)
// R1-R13: see session journal. R14: re-anchor 229.4us.
// R15: FAILED (1356us) -- but ONLY because HIP LDS float atomicAdd = CAS
//   loop. The architecture (csr_fine eliminated, stream+accumulate) was
//   sound. R16: FAILED, fine-bucket write-amp at EPB 4096 (10.5B runs).
// R17: WIN (219). R18: part_prep@512 kept. R19: NULL (not concurrency-
//   bound). R20: NULL (chunk sort; gather sits on ~2TB/s fabric wall).
// R21: 211.7 best. R22: FAILED (367): direct scatter write-allocates 64B
//   per 4B write (WRITE 110MB vs 6.4 logical) -- staged radix is required.
// R23: R15 REVIVED with native ds_add_f32 via inline asm (the fix for its
//   one fatal flaw). Tile-granular partition (64-node buckets, EPB 8192 ->
//   21B arena runs, half of R16's amp), csr_fine DELETED, gather streams
//   the unsorted tile list (8 lanes/edge, 4-deep) into AccF[64][68] fp32
//   via ds_add_f32 (~1.6M ds-instr/layer ~ 7us); degree via native LDS int
//   atomics; wave-local pack+MFMA unchanged. Pre-commit: gather>60 ->
//   revert to R21; part>70 -> granularity. Predicted 211.7 -> ~170-185.

constexpr int TSHIFT = 6;               // 64-node tiles == gather tile
constexpr int EPB    = 8192;            // edges per partition block (R23)
constexpr int PTHR   = 512;             // partition block threads
constexpr int EPT    = EPB / PTHR;      // 16 edges/thread
constexpr int CAP    = 2048;            // arena capacity per tile (mean 1024)
constexpr int BPT    = 4;               // bins per thread in partition scan
constexpr int BINMAX = PTHR * BPT;      // 2048 >= NBUCK=1563
constexpr int ASTR   = 68;              // AccF row stride (floats), 16B-aligned

// frag-packed bf16 weight image (shorts). Fragment = 16 lanes x 8 shorts =
// 128 shorts; flat idx = (((c*KK + kk)*4 + quad)*16 + m)*8 + j.
constexpr int W1F_OFF = 0;              // 4x2x4 frags  = 4096 shorts
constexpr int W2F_OFF = 4096;           // 4096
constexpr int W3F_OFF = 8192;           // 8x2x4 frags  = 8192
constexpr int W4F_OFF = 16384;          // 3x4x4 frags  = 6144 (cols padded 48)
constexpr int WIMG_TOT = 22528;

typedef __attribute__((ext_vector_type(8))) short short8;   // 8 bf16
typedef __attribute__((ext_vector_type(4))) float floatx4;  // MFMA acc

__device__ __forceinline__ float sigmoidf(float x) {
    return 1.0f / (1.0f + __expf(-x));
}
__device__ __forceinline__ unsigned short f2bf(float f) {   // RNE f32->bf16
    unsigned int u = __float_as_uint(f);
    u = (u + 0x7FFFu + ((u >> 16) & 1u)) >> 16;
    return (unsigned short)u;
}

// Native LDS float atomic add: 8 consecutive floats at LDS byte offset boff.
// (HIP atomicAdd(float*) on LDS = CAS loop -- R15's wall. ds_add_f32 is the
// hardware instruction; offsets assume the kernel's single __shared__ block
// starts at LDS offset 0.)
__device__ __forceinline__ void ds_add8(unsigned boff, uint4 v) {
    float f0 = __uint_as_float(v.x << 16);
    float f1 = __uint_as_float(v.x & 0xFFFF0000u);
    float f2 = __uint_as_float(v.y << 16);
    float f3 = __uint_as_float(v.y & 0xFFFF0000u);
    float f4 = __uint_as_float(v.z << 16);
    float f5 = __uint_as_float(v.z & 0xFFFF0000u);
    float f6 = __uint_as_float(v.w << 16);
    float f7 = __uint_as_float(v.w & 0xFFFF0000u);
    asm volatile("ds_add_f32 %0, %1"           :: "v"(boff), "v"(f0));
    asm volatile("ds_add_f32 %0, %1 offset:4"  :: "v"(boff), "v"(f1));
    asm volatile("ds_add_f32 %0, %1 offset:8"  :: "v"(boff), "v"(f2));
    asm volatile("ds_add_f32 %0, %1 offset:12" :: "v"(boff), "v"(f3));
    asm volatile("ds_add_f32 %0, %1 offset:16" :: "v"(boff), "v"(f4));
    asm volatile("ds_add_f32 %0, %1 offset:20" :: "v"(boff), "v"(f5));
    asm volatile("ds_add_f32 %0, %1 offset:24" :: "v"(boff), "v"(f6));
    asm volatile("ds_add_f32 %0, %1 offset:28" :: "v"(boff), "v"(f7));
}

// ---------------- tile partition + one-time prep (merged launch) -----------
// Blocks [0,gP): radix-partition 8192 edges into per-TILE arena regions
//   (1563 tiles; 4-bins/thread scan; LDS staging keeps arena writes in
//   21B runs per bucket per block).
// Blocks [gP,..): feat fp32->bf16 cast + frag-packed weight image build.
__global__ __launch_bounds__(PTHR) void part_prep_k(
    const int* __restrict__ src, const int* __restrict__ dst,
    int* __restrict__ ccur, int* __restrict__ arena, int E, int NBUCK, int gP,
    const float* __restrict__ feat, unsigned short* __restrict__ featbf,
    const float* __restrict__ W1, const float* __restrict__ W2,
    const float* __restrict__ W3, const float* __restrict__ W4,
    unsigned short* __restrict__ img, int n8)
{
    __shared__ int  histA[BINMAX];          // counts -> lcur (in place)
    __shared__ int  deltaA[BINMAX];         // global_base - block_excl
    __shared__ int  wsum[8];
    __shared__ int  stage[EPB];
    __shared__ unsigned short stageS[EPB];  // tile id per staged edge

    const int tid = threadIdx.x;

    if ((int)blockIdx.x >= gP) {
        // ---- prep path ----
        int i = ((int)blockIdx.x - gP) * PTHR + tid;
        if (i < n8) {
            const float4* p = (const float4*)feat + (size_t)i * 2;
            float4 a = p[0], b = p[1];
            uint4 o;
            o.x = (unsigned)f2bf(a.x) | ((unsigned)f2bf(a.y) << 16);
            o.y = (unsigned)f2bf(a.z) | ((unsigned)f2bf(a.w) << 16);
            o.z = (unsigned)f2bf(b.x) | ((unsigned)f2bf(b.y) << 16);
            o.w = (unsigned)f2bf(b.z) | ((unsigned)f2bf(b.w) << 16);
            ((uint4*)featbf)[i] = o;
            return;
        }
        int t = i - n8;
        if (t >= WIMG_TOT) return;
        float v = 0.f;
        int s = t;
        if (s < W2F_OFF) {                       // W1 [64x64]
            int j = s & 7, m = (s >> 3) & 15, q = (s >> 7) & 3, kk = (s >> 9) & 1, c = s >> 10;
            v = W1[(kk * 32 + q * 8 + j) * 64 + c * 16 + m];
        } else if (s < W3F_OFF) {                // W2 [64x64]
            s -= W2F_OFF;
            int j = s & 7, m = (s >> 3) & 15, q = (s >> 7) & 3, kk = (s >> 9) & 1, c = s >> 10;
            v = W2[(kk * 32 + q * 8 + j) * 64 + c * 16 + m];
        } else if (s < W4F_OFF) {                // W3 [64x128]
            s -= W3F_OFF;
            int j = s & 7, m = (s >> 3) & 15, q = (s >> 7) & 3, kk = (s >> 9) & 1, c = s >> 10;
            v = W3[(kk * 32 + q * 8 + j) * 128 + c * 16 + m];
        } else {                                 // W4 [128x40], cols padded 48
            s -= W4F_OFF;
            int j = s & 7, m = (s >> 3) & 15, q = (s >> 7) & 3, kk = (s >> 9) & 3, c = s >> 11;
            int n = c * 16 + m;
            if (n < 40) v = W4[(kk * 32 + q * 8 + j) * 40 + n];
        }
        img[t] = f2bf(v);
        return;
    }

    // ---- partition path ----
    const int e0  = blockIdx.x * EPB;
    const int ec  = min(EPB, E - e0);
    const int lane = tid & 63, wid = tid >> 6;

    int pk[EPT], bk[EPT];
    #pragma unroll
    for (int k = 0; k < BPT; k++) histA[tid * BPT + k] = 0;
    __syncthreads();
    #pragma unroll
    for (int j = 0; j < EPT; j++) {
        int idx = tid + j * PTHR;
        if (idx < ec) {
            int s = src[e0 + idx];
            int d = dst[e0 + idx];
            bk[j] = d >> TSHIFT;                 // tile id (0..1562)
            pk[j] = s | ((d & 63) << 17);        // src 17b | fine-node 6b
            atomicAdd(&histA[bk[j]], 1);
        } else bk[j] = -1;
    }
    __syncthreads();
    // 4-bins/thread local sums -> 512-wide shuffle scan -> per-bin offsets
    int loc[BPT];
    int ssum = 0;
    #pragma unroll
    for (int k = 0; k < BPT; k++) {
        loc[k] = ssum;
        ssum += histA[tid * BPT + k];
    }
    int v = ssum;
    #pragma unroll
    for (int d = 1; d < 64; d <<= 1) {
        int t = __shfl_up(v, d);
        if (lane >= d) v += t;
    }
    if (lane == 63) wsum[wid] = v;
    __syncthreads();
    if (tid == 0) {
        int s = 0;
        #pragma unroll
        for (int k = 0; k < 8; k++) { int t = wsum[k]; wsum[k] = s; s += t; }
    }
    __syncthreads();
    const int base0 = wsum[wid] + v - ssum;
    #pragma unroll
    for (int k = 0; k < BPT; k++) {
        int b  = tid * BPT + k;
        int h  = histA[b];
        int ex = base0 + loc[k];
        int gb = 0;
        if (b < NBUCK && h > 0) gb = atomicAdd(ccur + b, h);
        deltaA[b] = gb - ex;
        histA[b]  = ex;                          // becomes lcur
    }
    __syncthreads();
    #pragma unroll
    for (int j = 0; j < EPT; j++) {
        if (bk[j] >= 0) {
            int l = atomicAdd(&histA[bk[j]], 1);
            stage[l]  = pk[j];
            stageS[l] = (unsigned short)bk[j];
        }
    }
    __syncthreads();
    for (int i = tid; i < ec; i += PTHR) {
        int b = stageS[i];
        arena[(size_t)b * CAP + i + deltaA[b]] = stage[i];
    }
}

// ---------------- divergence-free tile gather (ds_add_f32 accumulate) ------
// 8-lane group per edge (full 128B row coalesced), 4 edges in flight;
// native ds_add_f32 into AccF[64][68]; degree via native LDS int atomic.
// Then wave-local pack of OWN rows into Agg (MFMA A layout, rows 16w..+15).
__device__ __forceinline__ void gather_accum(
    const unsigned short* __restrict__ h, const int* __restrict__ ebase,
    int ec, float* AccF, int* degL, unsigned short* Agg,
    unsigned accf_base, int tid)
{
    #pragma unroll
    for (int k = 0; k < 17; k++) AccF[tid + k * 256] = 0.f;
    if (tid < 64) degL[tid] = 0;
    __syncthreads();

    const int l8 = tid & 7, q = l8 * 8;
    const int grp = tid >> 3;
    int i = grp;
    for (; i + 96 < ec; i += 128) {              // 4 edges in flight / lane
        int ea = ebase[i], eb = ebase[i + 32];
        int ecx = ebase[i + 64], ed = ebase[i + 96];
        uint4 va = *(const uint4*)(h + (size_t)(ea & 0x1FFFF) * 64 + q);
        uint4 vb = *(const uint4*)(h + (size_t)(eb & 0x1FFFF) * 64 + q);
        uint4 vc = *(const uint4*)(h + (size_t)(ecx & 0x1FFFF) * 64 + q);
        uint4 vd = *(const uint4*)(h + (size_t)(ed & 0x1FFFF) * 64 + q);
        int fa = (ea >> 17) & 63, fb = (eb >> 17) & 63;
        int fc = (ecx >> 17) & 63, fd = (ed >> 17) & 63;
        ds_add8(accf_base + (unsigned)(fa * ASTR + q) * 4u, va);
        ds_add8(accf_base + (unsigned)(fb * ASTR + q) * 4u, vb);
        ds_add8(accf_base + (unsigned)(fc * ASTR + q) * 4u, vc);
        ds_add8(accf_base + (unsigned)(fd * ASTR + q) * 4u, vd);
        if (l8 == 0) {
            atomicAdd(&degL[fa], 1); atomicAdd(&degL[fb], 1);
            atomicAdd(&degL[fc], 1); atomicAdd(&degL[fd], 1);
        }
    }
    for (; i < ec; i += 32) {
        int ea = ebase[i];
        uint4 va = *(const uint4*)(h + (size_t)(ea & 0x1FFFF) * 64 + q);
        int fa = (ea >> 17) & 63;
        ds_add8(accf_base + (unsigned)(fa * ASTR + q) * 4u, va);
        if (l8 == 0) atomicAdd(&degL[fa], 1);
    }
    __syncthreads();

    // wave-local pack: thread tid -> row = tid>>2 (wave w owns 16w..16w+15)
    const int row = tid >> 2, c0 = (tid & 3) * 16;
    const float inv = __builtin_amdgcn_rcpf((float)max(degL[row], 1));
    const float4* Ar = (const float4*)(AccF + row * ASTR + c0);
    float4 x0 = Ar[0], x1 = Ar[1], x2 = Ar[2], x3 = Ar[3];
    uint4 o0, o1;
    o0.x = (unsigned)f2bf(x0.x * inv) | ((unsigned)f2bf(x0.y * inv) << 16);
    o0.y = (unsigned)f2bf(x0.z * inv) | ((unsigned)f2bf(x0.w * inv) << 16);
    o0.z = (unsigned)f2bf(x1.x * inv) | ((unsigned)f2bf(x1.y * inv) << 16);
    o0.w = (unsigned)f2bf(x1.z * inv) | ((unsigned)f2bf(x1.w * inv) << 16);
    o1.x = (unsigned)f2bf(x2.x * inv) | ((unsigned)f2bf(x2.y * inv) << 16);
    o1.y = (unsigned)f2bf(x2.z * inv) | ((unsigned)f2bf(x2.w * inv) << 16);
    o1.z = (unsigned)f2bf(x3.x * inv) | ((unsigned)f2bf(x3.y * inv) << 16);
    o1.w = (unsigned)f2bf(x3.z * inv) | ((unsigned)f2bf(x3.w * inv) << 16);
    *(uint4*)(Agg + row * 72 + c0)     = o0;
    *(uint4*)(Agg + row * 72 + c0 + 8) = o1;
}

// ---------------- fused gather + GEMM1 + sigmoid -> t1 ---------------------
// 256 threads / 64-row tile, grid 1563 (87% CU coverage). LDS 26.9KB.
__global__ __launch_bounds__(256) void aggemm1_k(
    const unsigned short* __restrict__ featbf, const int* __restrict__ ccur,
    const int* __restrict__ arena, const unsigned short* __restrict__ img,
    const float* __restrict__ bias, unsigned short* __restrict__ t1, int N)
{
    __shared__ alignas(16) unsigned char SMEM[17408 + 9216 + 256];
    float*          AccF = (float*)SMEM;                  // @0 (asm offsets!)
    unsigned short* Agg  = (unsigned short*)(SMEM + 17408);
    int*            degL = (int*)(SMEM + 17408 + 9216);

    const int tid = threadIdx.x;
    const int tile = blockIdx.x;
    const int rowB = tile * 64;
    const int w = tid >> 6, lane = tid & 63;
    const int m = lane & 15, quad = lane >> 4;
    const int row0 = rowB + w * 16;

    gather_accum(featbf, arena + (size_t)tile * CAP, min(ccur[tile], CAP),
                 AccF, degL, Agg, 0u, tid);

    const short8* Wf = (const short8*)(img + W1F_OFF);
    floatx4 acc[4];
    #pragma unroll
    for (int c = 0; c < 4; c++) acc[c] = (floatx4){0.f, 0.f, 0.f, 0.f};
    #pragma unroll
    for (int kk = 0; kk < 2; kk++) {
        short8 a = *(const short8*)(Agg + (w * 16 + m) * 72 + kk * 32 + quad * 8);
        #pragma unroll
        for (int c = 0; c < 4; c++) {
            short8 b = Wf[((c * 2 + kk) * 4 + quad) * 16 + m];
            acc[c] = __builtin_amdgcn_mfma_f32_16x16x32_bf16(a, b, acc[c], 0, 0, 0);
        }
    }
    bool dzr[4];
    int rows[4];
    #pragma unroll
    for (int r = 0; r < 4; r++) {
        rows[r] = row0 + quad * 4 + r;
        dzr[r] = (degL[w * 16 + quad * 4 + r] == 0);
    }
    #pragma unroll
    for (int c = 0; c < 4; c++) {
        int col = c * 16 + m;
        float bv = bias[col];
        #pragma unroll
        for (int r = 0; r < 4; r++) {
            if (rows[r] < N) {
                float v = dzr[r] ? 0.5f : sigmoidf(acc[c][r] + bv);
                t1[(size_t)rows[r] * 64 + col] = f2bf(v);
            }
        }
    }
}

// ---------------- fused gather + triple-GEMM -> out ------------------------
// 256 threads / 64-row tile. LDS: AccF 17408 | Agg 9216 | T2 9216 | degL.
// Agg/T2/H3h rows are wave-local -> no barrier after the gather barrier.
__global__ __launch_bounds__(256) void aggep3_k(
    const unsigned short* __restrict__ t1, const int* __restrict__ ccur,
    const int* __restrict__ arena, const unsigned short* __restrict__ img,
    const float* __restrict__ b2, const float* __restrict__ b3,
    const float* __restrict__ b4, float* __restrict__ out, int N)
{
    __shared__ alignas(16) unsigned char SMEM[17408 + 9216 + 9216 + 256];
    float*          AccF = (float*)SMEM;                  // @0 (asm offsets!)
    unsigned short* Agg  = (unsigned short*)(SMEM + 17408);
    unsigned short* T2   = (unsigned short*)(SMEM + 17408 + 9216);
    unsigned short* H3h  = Agg;                           // Agg dead after ph0
    int*            degL = (int*)(SMEM + 17408 + 9216 + 9216);

    const int tid = threadIdx.x;
    const int tile = blockIdx.x;
    const int rowB = tile * 64;
    const int w = tid >> 6, lane = tid & 63;
    const int m = lane & 15, quad = lane >> 4;
    const int row0 = rowB + w * 16;

    gather_accum(t1, arena + (size_t)tile * CAP, min(ccur[tile], CAP),
                 AccF, degL, Agg, 0u, tid);

    // ---- phase 0: T2 = sigmoid(Agg @ W2 + b2) ----
    {
        const short8* Wf = (const short8*)(img + W2F_OFF);
        floatx4 acc[4];
        #pragma unroll
        for (int c = 0; c < 4; c++) acc[c] = (floatx4){0.f, 0.f, 0.f, 0.f};
        #pragma unroll
        for (int kk = 0; kk < 2; kk++) {
            short8 a = *(const short8*)(Agg + (w * 16 + m) * 72 + kk * 32 + quad * 8);
            #pragma unroll
            for (int c = 0; c < 4; c++) {
                short8 b = Wf[((c * 2 + kk) * 4 + quad) * 16 + m];
                acc[c] = __builtin_amdgcn_mfma_f32_16x16x32_bf16(a, b, acc[c], 0, 0, 0);
            }
        }
        bool dzr[4];
        #pragma unroll
        for (int r = 0; r < 4; r++)
            dzr[r] = (degL[w * 16 + quad * 4 + r] == 0);
        #pragma unroll
        for (int c = 0; c < 4; c++) {
            int col = c * 16 + m;
            float bv = b2[col];
            #pragma unroll
            for (int r = 0; r < 4; r++) {
                int rl = w * 16 + quad * 4 + r;
                float v = dzr[r] ? 0.5f : sigmoidf(acc[c][r] + bv);
                T2[rl * 72 + col] = f2bf(v);
            }
        }
    }

    // ---- phases 1&2 split-K: per half, H3h = relu(T2@W3half+b3half),
    //      then acc2 += H3h @ W4[khalf] ----
    floatx4 acc2[3];
    #pragma unroll
    for (int c = 0; c < 3; c++) acc2[c] = (floatx4){0.f, 0.f, 0.f, 0.f};
    const short8* Wf3 = (const short8*)(img + W3F_OFF);
    const short8* Wf4 = (const short8*)(img + W4F_OFF);

    #pragma unroll
    for (int half = 0; half < 2; half++) {
        floatx4 acc[4];
        #pragma unroll
        for (int c = 0; c < 4; c++) acc[c] = (floatx4){0.f, 0.f, 0.f, 0.f};
        #pragma unroll
        for (int kk = 0; kk < 2; kk++) {
            short8 a = *(const short8*)(T2 + (w * 16 + m) * 72 + kk * 32 + quad * 8);
            #pragma unroll
            for (int c = 0; c < 4; c++) {
                short8 b = Wf3[(((half * 4 + c) * 2 + kk) * 4 + quad) * 16 + m];
                acc[c] = __builtin_amdgcn_mfma_f32_16x16x32_bf16(a, b, acc[c], 0, 0, 0);
            }
        }
        #pragma unroll
        for (int c = 0; c < 4; c++) {
            int col = c * 16 + m;
            float bv = b3[half * 64 + col];
            #pragma unroll
            for (int r = 0; r < 4; r++) {
                int rl = w * 16 + quad * 4 + r;
                H3h[rl * 72 + col] = f2bf(fmaxf(acc[c][r] + bv, 0.f));
            }
        }
        #pragma unroll
        for (int kk2 = 0; kk2 < 2; kk2++) {
            short8 a = *(const short8*)(H3h + (w * 16 + m) * 72 + kk2 * 32 + quad * 8);
            #pragma unroll
            for (int c = 0; c < 3; c++) {
                short8 b = Wf4[((c * 4 + half * 2 + kk2) * 4 + quad) * 16 + m];
                acc2[c] = __builtin_amdgcn_mfma_f32_16x16x32_bf16(a, b, acc2[c], 0, 0, 0);
            }
        }
    }

    // ---- store out = acc2 + b4 ----
    #pragma unroll
    for (int c = 0; c < 3; c++) {
        int col = c * 16 + m;
        if (col < 40) {
            float bv = b4[col];
            #pragma unroll
            for (int r = 0; r < 4; r++) {
                int row = row0 + quad * 4 + r;
                if (row < N) out[(size_t)row * 40 + col] = acc2[c][r] + bv;
            }
        }
    }
}

extern "C" void kernel_launch(void* const* d_in, const int* in_sizes, int n_in,
                              void* d_out, int out_size, void* d_ws, size_t ws_size,
                              hipStream_t stream)
{
    const float* feat = (const float*)d_in[0];
    const int*   eidx = (const int*)d_in[1];
    const float* W1 = (const float*)d_in[2];
    const float* b1 = (const float*)d_in[3];
    const float* W2 = (const float*)d_in[4];
    const float* b2 = (const float*)d_in[5];
    const float* W3 = (const float*)d_in[6];
    const float* b3 = (const float*)d_in[7];
    const float* W4 = (const float*)d_in[8];
    const float* b4 = (const float*)d_in[9];

    const int N = in_sizes[0] / 64;
    const int E = in_sizes[1] / 2;
    const int* src = eidx;
    const int* dst = eidx + E;

    const int NBUCK = (N + 63) >> TSHIFT;          // 1563 tiles

    unsigned short* featbf = (unsigned short*)d_ws;            // N*64 bf16
    unsigned short* t1     = featbf + (size_t)N * 64;          // N*64 bf16
    unsigned short* img    = t1     + (size_t)N * 64;          // WIMG_TOT
    int*   ccur  = (int*)(img + WIMG_TOT);                     // NBUCK
    int*   arena = ccur + NBUCK;                               // NBUCK*CAP
    float* out   = (float*)d_out;

    hipMemsetAsync(ccur, 0, (size_t)NBUCK * sizeof(int), stream);

    const int gP  = (E + EPB - 1) / EPB;           // 196 partition blocks
    const int n8  = N * 64 / 8;
    const int gPC = (n8 + WIMG_TOT + PTHR - 1) / PTHR;

    // tile-granular partition + prep (merged); csr_fine eliminated (R23)
    part_prep_k<<<gP + gPC, dim3(PTHR), 0, stream>>>(src, dst, ccur, arena, E,
                                                     NBUCK, gP, feat, featbf,
                                                     W1, W2, W3, W4, img, n8);

    // t1 = sigmoid(mean(featbf[src]) @ W1 + b1)
    aggemm1_k<<<NBUCK, dim3(256), 0, stream>>>(featbf, ccur, arena, img, b1, t1, N);
    // out = relu(sigmoid(mean(t1[src])@W2+b2)@W3+b3)@W4 + b4
    aggep3_k<<<NBUCK, dim3(256), 0, stream>>>(t1, ccur, arena, img, b2, b3, b4, out, N);
}

// Round 11
// 216.701 us; speedup vs baseline: 6.0663x; 6.0663x over previous
//
#include <hip/hip_runtime.h>

// HGCN on MI355X. logmap0(expmap0(v)) == v here, so the model reduces to:
//   t1 = sigmoid(segmean(feat@W1+b1)); t2 = sigmoid(segmean(t1@W2+b2))
//   out = relu(t2@W3+b3)@W4 + b4     (segmean commutes with the linear map;
//   deg-0 nodes: segmean = 0 -> value 0.5 exactly, handled via dz check)
// R1-R13: see session journal. R14: re-anchor 229.4us.
// R15: FAILED. R16: FAILED (fine-bucket write-amp). R17: WIN (219).
// R18: part_prep@512 kept. R19: NULL (not concurrency-bound).
// R20: NULL -- but CONFOUNDED: 3125 blocks = 12 serial rounds/CU, so block
//   start times were smeared; chunk order alone can't align cross-block.
// R21: 211.7 BEST. R22: FAILED (367; 4B scatter write-amp, WRITE 110MB).
// R23: FAILED (1315). Native ds_add_f32 == CAS-loop time (609us both) =>
//   LDS atomic THROUGHPUT ~3.6 cyc/lane-op is the wall, not the encoding.
//   102M lane-atomics can never work. Payload stays in registers.
// R24: synchronized chunk-walk gather. csr_fine sorts by (fine<<3)|chunk
//   (2048 bins) emitting off2[8N+1] bin boundaries (rows stay contiguous,
//   R17 stream loop unchanged -- only the ORDER within a row changes);
//   gather blocks 128 rows/512thr, grid 782 <= 4 blocks/CU by LDS => ALL
//   co-resident. All waves walk chunks together: active source window
//   ~2-4MB fits every XCD L2 -> 16x source reuse captured.
//   Pre-commit: FETCH 79->20-40MB & dur->~32 => win (~175-190 total);
//   FETCH unchanged => gather rooflined, stop attacking it.

constexpr int CSHIFT = 8;               // 256 nodes per coarse bucket
constexpr int CNODES = 1 << CSHIFT;
constexpr int EPB    = 4096;            // edges per partition block
constexpr int PTHR   = 512;             // partition block threads
constexpr int EPT    = EPB / PTHR;      // 8 edges/thread
constexpr int CAP    = 6144;            // arena cap/bucket (mean 4082)
constexpr int SSH    = 14;              // src chunk shift (16K rows = 2MB bf16)
constexpr int NBIN   = CNODES * 8;      // 2048 sort bins per bucket

// frag-packed bf16 weight image (shorts). Fragment = 16 lanes x 8 shorts =
// 128 shorts; flat idx = (((c*KK + kk)*4 + quad)*16 + m)*8 + j.
constexpr int W1F_OFF = 0;              // 4x2x4 frags  = 4096 shorts
constexpr int W2F_OFF = 4096;           // 4096
constexpr int W3F_OFF = 8192;           // 8x2x4 frags  = 8192
constexpr int W4F_OFF = 16384;          // 3x4x4 frags  = 6144 (cols padded 48)
constexpr int WIMG_TOT = 22528;

typedef __attribute__((ext_vector_type(8))) short short8;   // 8 bf16
typedef __attribute__((ext_vector_type(4))) float floatx4;  // MFMA acc

__device__ __forceinline__ float sigmoidf(float x) {
    return 1.0f / (1.0f + __expf(-x));
}
__device__ __forceinline__ unsigned short f2bf(float f) {   // RNE f32->bf16
    unsigned int u = __float_as_uint(f);
    u = (u + 0x7FFFu + ((u >> 16) & 1u)) >> 16;
    return (unsigned short)u;
}

// ---------------- CSR partition + one-time prep (merged launch) ------------
// R21-proven: blocks [0,gP) radix-partition edges into per-bucket arenas;
// blocks [gP,..) do feat cast + weight image.
__global__ __launch_bounds__(512) void part_prep_k(
    const int* __restrict__ src, const int* __restrict__ dst,
    int* __restrict__ ccur, int* __restrict__ arena, int E, int NBUCK, int gP,
    const float* __restrict__ feat, unsigned short* __restrict__ featbf,
    const float* __restrict__ W1, const float* __restrict__ W2,
    const float* __restrict__ W3, const float* __restrict__ W4,
    unsigned short* __restrict__ img, int n8)
{
    __shared__ int  hist[512];
    __shared__ int  exoff[512];
    __shared__ int  lcur[512];
    __shared__ int  gbase[512];
    __shared__ int  wsum[8];
    __shared__ int  stage[EPB];
    __shared__ unsigned short stageS[EPB];   // bucket id (up to 390)

    const int tid = threadIdx.x;

    if ((int)blockIdx.x >= gP) {
        // ---- prep path ----
        int i = ((int)blockIdx.x - gP) * PTHR + tid;
        if (i < n8) {
            const float4* p = (const float4*)feat + (size_t)i * 2;
            float4 a = p[0], b = p[1];
            uint4 o;
            o.x = (unsigned)f2bf(a.x) | ((unsigned)f2bf(a.y) << 16);
            o.y = (unsigned)f2bf(a.z) | ((unsigned)f2bf(a.w) << 16);
            o.z = (unsigned)f2bf(b.x) | ((unsigned)f2bf(b.y) << 16);
            o.w = (unsigned)f2bf(b.z) | ((unsigned)f2bf(b.w) << 16);
            ((uint4*)featbf)[i] = o;
            return;
        }
        int t = i - n8;
        if (t >= WIMG_TOT) return;
        float v = 0.f;
        int s = t;
        if (s < W2F_OFF) {                       // W1 [64x64]
            int j = s & 7, m = (s >> 3) & 15, q = (s >> 7) & 3, kk = (s >> 9) & 1, c = s >> 10;
            v = W1[(kk * 32 + q * 8 + j) * 64 + c * 16 + m];
        } else if (s < W3F_OFF) {                // W2 [64x64]
            s -= W2F_OFF;
            int j = s & 7, m = (s >> 3) & 15, q = (s >> 7) & 3, kk = (s >> 9) & 1, c = s >> 10;
            v = W2[(kk * 32 + q * 8 + j) * 64 + c * 16 + m];
        } else if (s < W4F_OFF) {                // W3 [64x128]
            s -= W3F_OFF;
            int j = s & 7, m = (s >> 3) & 15, q = (s >> 7) & 3, kk = (s >> 9) & 1, c = s >> 10;
            v = W3[(kk * 32 + q * 8 + j) * 128 + c * 16 + m];
        } else {                                 // W4 [128x40], cols padded 48
            s -= W4F_OFF;
            int j = s & 7, m = (s >> 3) & 15, q = (s >> 7) & 3, kk = (s >> 9) & 3, c = s >> 11;
            int n = c * 16 + m;
            if (n < 40) v = W4[(kk * 32 + q * 8 + j) * 40 + n];
        }
        img[t] = f2bf(v);
        return;
    }

    // ---- partition path (512 threads, 512-entry hist) ----
    const int e0  = blockIdx.x * EPB;
    const int ec  = min(EPB, E - e0);
    const int lane = tid & 63, wid = tid >> 6;

    int pk[EPT], bk[EPT];
    hist[tid] = 0;
    __syncthreads();
    #pragma unroll
    for (int j = 0; j < EPT; j++) {
        int idx = tid + j * PTHR;
        if (idx < ec) {
            int s = src[e0 + idx];
            int d = dst[e0 + idx];
            bk[j] = d >> CSHIFT;
            pk[j] = s | ((d & (CNODES - 1)) << 17);
            atomicAdd(&hist[bk[j]], 1);
        } else bk[j] = -1;
    }
    __syncthreads();
    int h = hist[tid];
    int v = h;
    #pragma unroll
    for (int d = 1; d < 64; d <<= 1) {
        int t = __shfl_up(v, d);
        if (lane >= d) v += t;
    }
    if (lane == 63) wsum[wid] = v;
    __syncthreads();
    if (tid == 0) {
        int s = 0;
        #pragma unroll
        for (int k = 0; k < 8; k++) { int t = wsum[k]; wsum[k] = s; s += t; }
    }
    __syncthreads();
    {
        int ex = wsum[wid] + v - h;
        int gb = 0;
        if (tid < NBUCK && h > 0) gb = atomicAdd(ccur + tid, h);
        exoff[tid] = ex;
        lcur[tid]  = ex;
        gbase[tid] = gb;
    }
    __syncthreads();
    #pragma unroll
    for (int j = 0; j < EPT; j++) {
        if (bk[j] >= 0) {
            int l = atomicAdd(&lcur[bk[j]], 1);
            stage[l]  = pk[j];
            stageS[l] = (unsigned short)bk[j];
        }
    }
    __syncthreads();
    for (int i = tid; i < ec; i += PTHR) {
        int b = stageS[i];
        arena[(size_t)b * CAP + gbase[b] + (i - exoff[b])] = stage[i];
    }
}

// One 1024-thr block per 256-node bucket (391 blocks). R24: counting sort
// over 2048 bins, key = (fine<<3)|chunk; writes ALL bin boundaries to
// off2[node*8+c] -> per-row ranges contiguous AND chunk-ordered.
__global__ __launch_bounds__(1024) void csr_fine(const int* __restrict__ arena,
                                                 const int* __restrict__ ccur,
                                                 int* __restrict__ off2,
                                                 int* __restrict__ ssrc,
                                                 int N, int E, int NBUCK) {
    __shared__ int part[512];
    __shared__ int cnt[NBIN];
    __shared__ int cur[NBIN];
    __shared__ int wpre[8];
    __shared__ int wpre2[16];
    const int b = blockIdx.x;
    const int node0 = b << CSHIFT;
    const int tid = threadIdx.x;
    const int lane = tid & 63, wid = tid >> 6;

    // cross-bucket inclusive scan of ccur (NBUCK<=512) via 8-wave shuffle
    int c0 = 0, v0 = 0;
    if (tid < 512) {
        c0 = (tid < NBUCK) ? ccur[tid] : 0;
        v0 = c0;
        #pragma unroll
        for (int d = 1; d < 64; d <<= 1) {
            int t = __shfl_up(v0, d);
            if (lane >= d) v0 += t;
        }
        if (lane == 63) wpre[wid] = v0;
    }
    __syncthreads();
    if (tid == 0) {
        int s = 0;
        #pragma unroll
        for (int k = 0; k < 8; k++) { int t = wpre[k]; wpre[k] = s; s += t; }
    }
    __syncthreads();
    if (tid < 512) part[tid] = wpre[wid] + v0;
    __syncthreads();
    const int cbeg = (b > 0) ? part[b - 1] : 0;
    const int ec   = min(ccur[b], CAP);
    if (b == 0 && tid == 0) off2[8 * N] = E;

    cnt[tid] = 0;
    cnt[tid + 1024] = 0;
    __syncthreads();
    const int* pe = arena + (size_t)b * CAP;
    for (int i = tid; i < ec; i += 1024) {
        int p = pe[i];
        int key = (((p >> 17) & (CNODES - 1)) << 3) | ((p & 0x1FFFF) >> SSH);
        atomicAdd(&cnt[key], 1);
    }
    __syncthreads();

    // scan 2048 bins: 2/thread serial + 16-wave shuffle scan
    const int t2 = tid * 2;
    int s0 = cnt[t2], s1 = cnt[t2 + 1];
    int tsum = s0 + s1;
    int v = tsum;
    #pragma unroll
    for (int d = 1; d < 64; d <<= 1) {
        int t = __shfl_up(v, d);
        if (lane >= d) v += t;
    }
    if (lane == 63) wpre2[wid] = v;
    __syncthreads();
    if (tid == 0) {
        int s = 0;
        #pragma unroll
        for (int k = 0; k < 16; k++) { int t = wpre2[k]; wpre2[k] = s; s += t; }
    }
    __syncthreads();
    const int ex0 = wpre2[wid] + v - tsum;     // exclusive prefix of bin t2
    cur[t2]     = ex0;
    cur[t2 + 1] = ex0 + s0;
    // bins t2, t2+1 share a node (t2 even -> t2&7 in {0,2,4,6})
    {
        int node = node0 + (t2 >> 3);
        if (node < N) {
            off2[node0 * 8 + t2]     = cbeg + ex0;
            off2[node0 * 8 + t2 + 1] = cbeg + ex0 + s0;
        }
    }
    __syncthreads();
    for (int i = tid; i < ec; i += 1024) {
        int p = pe[i];
        int key = (((p >> 17) & (CNODES - 1)) << 3) | ((p & 0x1FFFF) >> SSH);
        int pos = cbeg + atomicAdd(&cur[key], 1);
        ssrc[pos] = p & 0x1FFFF;
    }
}

// ---------------- wave-local gather: mean of h[src] rows into LDS tile -----
// Wave w gathers ITS OWN rows w*16..w*16+15 (2 passes x 8 rows x 8 lanes).
// R17-proven 8-deep stream loop UNCHANGED -- row range is [off2[8g],
// off2[8g+8]) (contiguous; internally chunk-ordered for L2 alignment).
#define ACC8(v)                                    \
    acc[0] += __uint_as_float((v).x << 16);        \
    acc[1] += __uint_as_float((v).x & 0xFFFF0000u);\
    acc[2] += __uint_as_float((v).y << 16);        \
    acc[3] += __uint_as_float((v).y & 0xFFFF0000u);\
    acc[4] += __uint_as_float((v).z << 16);        \
    acc[5] += __uint_as_float((v).z & 0xFFFF0000u);\
    acc[6] += __uint_as_float((v).w << 16);        \
    acc[7] += __uint_as_float((v).w & 0xFFFF0000u);

__device__ __forceinline__ void gather_tile_wave(
    const unsigned short* __restrict__ h, const int* __restrict__ off2,
    const int* __restrict__ ssrc, unsigned short* Agg, int rowB, int N,
    int w, int lane)
{
    #pragma unroll
    for (int pass = 0; pass < 2; pass++) {
        int rl = w * 16 + pass * 8 + (lane >> 3);
        int g  = rowB + rl;
        int q  = (lane & 7) * 8;
        uint4 p = make_uint4(0u, 0u, 0u, 0u);
        if (g < N) {
            int beg = off2[g * 8], end = off2[g * 8 + 8];
            float acc[8] = {0.f, 0.f, 0.f, 0.f, 0.f, 0.f, 0.f, 0.f};
            int i = beg;
            for (; i + 8 <= end; i += 8) {       // 8 loads in flight per lane
                uint4 v0 = *(const uint4*)(h + (size_t)ssrc[i]     * 64 + q);
                uint4 v1 = *(const uint4*)(h + (size_t)ssrc[i + 1] * 64 + q);
                uint4 v2 = *(const uint4*)(h + (size_t)ssrc[i + 2] * 64 + q);
                uint4 v3 = *(const uint4*)(h + (size_t)ssrc[i + 3] * 64 + q);
                uint4 v4 = *(const uint4*)(h + (size_t)ssrc[i + 4] * 64 + q);
                uint4 v5 = *(const uint4*)(h + (size_t)ssrc[i + 5] * 64 + q);
                uint4 v6 = *(const uint4*)(h + (size_t)ssrc[i + 6] * 64 + q);
                uint4 v7 = *(const uint4*)(h + (size_t)ssrc[i + 7] * 64 + q);
                ACC8(v0); ACC8(v1); ACC8(v2); ACC8(v3);
                ACC8(v4); ACC8(v5); ACC8(v6); ACC8(v7);
            }
            for (; i + 2 <= end; i += 2) {
                uint4 v0 = *(const uint4*)(h + (size_t)ssrc[i]     * 64 + q);
                uint4 v1 = *(const uint4*)(h + (size_t)ssrc[i + 1] * 64 + q);
                ACC8(v0); ACC8(v1);
            }
            for (; i < end; i++) {
                uint4 v = *(const uint4*)(h + (size_t)ssrc[i] * 64 + q);
                ACC8(v);
            }
            // v_rcp_f32: 2^-22 rel err, absorbed by the bf16 round
            float inv = __builtin_amdgcn_rcpf((float)max(end - beg, 1));
            p.x = (unsigned)f2bf(acc[0]*inv) | ((unsigned)f2bf(acc[1]*inv) << 16);
            p.y = (unsigned)f2bf(acc[2]*inv) | ((unsigned)f2bf(acc[3]*inv) << 16);
            p.z = (unsigned)f2bf(acc[4]*inv) | ((unsigned)f2bf(acc[5]*inv) << 16);
            p.w = (unsigned)f2bf(acc[6]*inv) | ((unsigned)f2bf(acc[7]*inv) << 16);
        }
        *(uint4*)(Agg + rl * 72 + q) = p;
    }
}

// ---------------- fused gather + GEMM1 + sigmoid -> t1 ---------------------
// R24: 512 threads / 128-row tile, grid 782 -> ALL blocks co-resident
// (LDS 18.4KB, <=4 blocks/CU) => chip-wide chunk-walk alignment.
__global__ __launch_bounds__(512) void aggemm1_k(
    const unsigned short* __restrict__ featbf, const int* __restrict__ off2,
    const int* __restrict__ ssrc, const unsigned short* __restrict__ img,
    const float* __restrict__ bias, unsigned short* __restrict__ t1, int N)
{
    __shared__ alignas(16) unsigned short Agg[128 * 72];   // 18.4 KB

    const int tid = threadIdx.x;
    const int rowB = blockIdx.x * 128;
    const int w = tid >> 6, lane = tid & 63;
    const int m = lane & 15, quad = lane >> 4;
    const int row0 = rowB + w * 16;

    gather_tile_wave(featbf, off2, ssrc, Agg, rowB, N, w, lane);

    const short8* Wf = (const short8*)(img + W1F_OFF);
    floatx4 acc[4];
    #pragma unroll
    for (int c = 0; c < 4; c++) acc[c] = (floatx4){0.f, 0.f, 0.f, 0.f};
    #pragma unroll
    for (int kk = 0; kk < 2; kk++) {
        short8 a = *(const short8*)(Agg + (w * 16 + m) * 72 + kk * 32 + quad * 8);
        #pragma unroll
        for (int c = 0; c < 4; c++) {
            short8 b = Wf[((c * 2 + kk) * 4 + quad) * 16 + m];
            acc[c] = __builtin_amdgcn_mfma_f32_16x16x32_bf16(a, b, acc[c], 0, 0, 0);
        }
    }
    bool dzr[4];
    int rows[4];
    #pragma unroll
    for (int r = 0; r < 4; r++) {
        rows[r] = row0 + quad * 4 + r;
        dzr[r] = (rows[r] < N) ? (off2[rows[r] * 8 + 8] == off2[rows[r] * 8]) : false;
    }
    #pragma unroll
    for (int c = 0; c < 4; c++) {
        int col = c * 16 + m;
        float bv = bias[col];
        #pragma unroll
        for (int r = 0; r < 4; r++) {
            if (rows[r] < N) {
                float v = dzr[r] ? 0.5f : sigmoidf(acc[c][r] + bv);
                t1[(size_t)rows[r] * 64 + col] = f2bf(v);
            }
        }
    }
}

// ---------------- fused gather + triple-GEMM -> out ------------------------
// 512 threads / 128-row tile; LDS: T2[0,9216) | Agg/H3h[9216,18432) shorts
// (36.9KB -> 4 blocks/CU). Rows wave-local -> no __syncthreads.
__global__ __launch_bounds__(512) void aggep3_k(
    const unsigned short* __restrict__ t1, const int* __restrict__ off2,
    const int* __restrict__ ssrc, const unsigned short* __restrict__ img,
    const float* __restrict__ b2, const float* __restrict__ b3,
    const float* __restrict__ b4, float* __restrict__ out, int N)
{
    __shared__ alignas(16) unsigned short SM[18432];   // 36.9 KB
    unsigned short* T2  = SM;            // 128 x 72
    unsigned short* Agg = SM + 9216;     // 128 x 72 (dead after phase 0)
    unsigned short* H3h = SM + 9216;     // aliases Agg

    const int tid = threadIdx.x;
    const int rowB = blockIdx.x * 128;
    const int w = tid >> 6, lane = tid & 63;
    const int m = lane & 15, quad = lane >> 4;
    const int row0 = rowB + w * 16;

    gather_tile_wave(t1, off2, ssrc, Agg, rowB, N, w, lane);

    // ---- phase 0: T2 = sigmoid(Agg @ W2 + b2) ----
    {
        const short8* Wf = (const short8*)(img + W2F_OFF);
        floatx4 acc[4];
        #pragma unroll
        for (int c = 0; c < 4; c++) acc[c] = (floatx4){0.f, 0.f, 0.f, 0.f};
        #pragma unroll
        for (int kk = 0; kk < 2; kk++) {
            short8 a = *(const short8*)(Agg + (w * 16 + m) * 72 + kk * 32 + quad * 8);
            #pragma unroll
            for (int c = 0; c < 4; c++) {
                short8 b = Wf[((c * 2 + kk) * 4 + quad) * 16 + m];
                acc[c] = __builtin_amdgcn_mfma_f32_16x16x32_bf16(a, b, acc[c], 0, 0, 0);
            }
        }
        bool dzr[4];
        #pragma unroll
        for (int r = 0; r < 4; r++) {
            int row = row0 + quad * 4 + r;
            dzr[r] = (row < N) ? (off2[row * 8 + 8] == off2[row * 8]) : false;
        }
        #pragma unroll
        for (int c = 0; c < 4; c++) {
            int col = c * 16 + m;
            float bv = b2[col];
            #pragma unroll
            for (int r = 0; r < 4; r++) {
                int rl = w * 16 + quad * 4 + r;
                float v = dzr[r] ? 0.5f : sigmoidf(acc[c][r] + bv);
                T2[rl * 72 + col] = f2bf(v);
            }
        }
    }

    // ---- phases 1&2 split-K: per half, H3h = relu(T2@W3half+b3half),
    //      then acc2 += H3h @ W4[khalf] ----
    floatx4 acc2[3];
    #pragma unroll
    for (int c = 0; c < 3; c++) acc2[c] = (floatx4){0.f, 0.f, 0.f, 0.f};
    const short8* Wf3 = (const short8*)(img + W3F_OFF);
    const short8* Wf4 = (const short8*)(img + W4F_OFF);

    #pragma unroll
    for (int half = 0; half < 2; half++) {
        floatx4 acc[4];
        #pragma unroll
        for (int c = 0; c < 4; c++) acc[c] = (floatx4){0.f, 0.f, 0.f, 0.f};
        #pragma unroll
        for (int kk = 0; kk < 2; kk++) {
            short8 a = *(const short8*)(T2 + (w * 16 + m) * 72 + kk * 32 + quad * 8);
            #pragma unroll
            for (int c = 0; c < 4; c++) {
                short8 b = Wf3[(((half * 4 + c) * 2 + kk) * 4 + quad) * 16 + m];
                acc[c] = __builtin_amdgcn_mfma_f32_16x16x32_bf16(a, b, acc[c], 0, 0, 0);
            }
        }
        #pragma unroll
        for (int c = 0; c < 4; c++) {
            int col = c * 16 + m;
            float bv = b3[half * 64 + col];
            #pragma unroll
            for (int r = 0; r < 4; r++) {
                int rl = w * 16 + quad * 4 + r;
                H3h[rl * 72 + col] = f2bf(fmaxf(acc[c][r] + bv, 0.f));
            }
        }
        #pragma unroll
        for (int kk2 = 0; kk2 < 2; kk2++) {
            short8 a = *(const short8*)(H3h + (w * 16 + m) * 72 + kk2 * 32 + quad * 8);
            #pragma unroll
            for (int c = 0; c < 3; c++) {
                short8 b = Wf4[((c * 4 + half * 2 + kk2) * 4 + quad) * 16 + m];
                acc2[c] = __builtin_amdgcn_mfma_f32_16x16x32_bf16(a, b, acc2[c], 0, 0, 0);
            }
        }
    }

    // ---- store out = acc2 + b4 ----
    #pragma unroll
    for (int c = 0; c < 3; c++) {
        int col = c * 16 + m;
        if (col < 40) {
            float bv = b4[col];
            #pragma unroll
            for (int r = 0; r < 4; r++) {
                int row = row0 + quad * 4 + r;
                if (row < N) out[(size_t)row * 40 + col] = acc2[c][r] + bv;
            }
        }
    }
}

extern "C" void kernel_launch(void* const* d_in, const int* in_sizes, int n_in,
                              void* d_out, int out_size, void* d_ws, size_t ws_size,
                              hipStream_t stream)
{
    const float* feat = (const float*)d_in[0];
    const int*   eidx = (const int*)d_in[1];
    const float* W1 = (const float*)d_in[2];
    const float* b1 = (const float*)d_in[3];
    const float* W2 = (const float*)d_in[4];
    const float* b2 = (const float*)d_in[5];
    const float* W3 = (const float*)d_in[6];
    const float* b3 = (const float*)d_in[7];
    const float* W4 = (const float*)d_in[8];
    const float* b4 = (const float*)d_in[9];

    const int N = in_sizes[0] / 64;
    const int E = in_sizes[1] / 2;
    const int* src = eidx;
    const int* dst = eidx + E;

    const int NBUCK = (N + CNODES - 1) / CNODES;   // 391

    unsigned short* featbf = (unsigned short*)d_ws;            // N*64 bf16
    unsigned short* t1     = featbf + (size_t)N * 64;          // N*64 bf16
    unsigned short* img    = t1     + (size_t)N * 64;          // WIMG_TOT
    int*   off2  = (int*)(img + WIMG_TOT);                     // 8N+1
    int*   ccur  = off2 + ((size_t)8 * N + 1);                 // NBUCK
    int*   ssrc  = ccur + NBUCK;                               // E
    int*   arena = ssrc + E;                                   // NBUCK*CAP
    float* out   = (float*)d_out;

    hipMemsetAsync(ccur, 0, (size_t)NBUCK * sizeof(int), stream);

    const int gP   = (E + EPB - 1) / EPB;
    const int g128 = (N + 127) / 128;              // 782, all co-resident
    const int n8   = N * 64 / 8;
    const int gPC  = (n8 + WIMG_TOT + PTHR - 1) / PTHR;

    // CSR partition + prep (merged, 512thr), then chunk-keyed counting sort
    part_prep_k<<<gP + gPC, dim3(PTHR), 0, stream>>>(src, dst, ccur, arena, E,
                                                     NBUCK, gP, feat, featbf,
                                                     W1, W2, W3, W4, img, n8);
    csr_fine<<<NBUCK, dim3(1024), 0, stream>>>(arena, ccur, off2, ssrc, N, E, NBUCK);

    // t1 = sigmoid(mean(featbf[src]) @ W1 + b1)   [fused, 0 barriers]
    aggemm1_k<<<g128, dim3(512), 0, stream>>>(featbf, off2, ssrc, img, b1, t1, N);
    // out = relu(sigmoid(mean(t1[src])@W2+b2)@W3+b3)@W4 + b4  [fused, 0 barriers]
    aggep3_k<<<g128, dim3(512), 0, stream>>>(t1, off2, ssrc, img, b2, b3, b4, out, N);
}